// Round 21
// baseline (100.497 us; speedup 1.0000x reference)
//
#include <hip/hip_runtime.h>

// LeNet forward, BATCH=4096. trunc = zero low 13 bits of fp32 mantissa.
// ALL layers via fp16 MFMA, hi-plane weights only (absmax stable 0.0156).
// conv1: 1 K-step MFMA, in-register pool. conv2: 19 K-steps (24-ic pad),
// B from L2, 64-MFMA bursts. fc1: LDS-FREE, barrier-free (A,B straight
// from L2 -- no reuse was protected by staging). fc2: wave/row dot.
// ws layout (bytes):
//   p1h  [4096][144][24] fp16 @ 0            (28,311,552)
//   p2h  [4096][800]     fp16 @ 28,311,552   ( 6,553,600)
//   h1h  [4096][512]     fp16 @ 34,865,152   ( 4,194,304)
//   wph  [20][64][32]    fp16 @ 39,059,456   (    81,920)
//   wpf1 [25][512][64]   fp16 @ 39,141,376   ( 1,638,400)
//   wpc1 [2][64][8]      fp16 @ 40,779,776   (     2,048)

typedef _Float16 v8h __attribute__((ext_vector_type(8)));
typedef float v4f __attribute__((ext_vector_type(4)));

__device__ __forceinline__ float trunc13(float v) {
    return __int_as_float(__float_as_int(v) & (int)0xFFFFE000u);
}

// ---------------------------------------------------------------------------
// K0: ALL weight prep in one kernel.
// ---------------------------------------------------------------------------
__global__ void k_prep(const float* __restrict__ w1, const float* __restrict__ w2,
                       const float* __restrict__ wf1,
                       _Float16* __restrict__ wpc1, _Float16* __restrict__ wph,
                       _Float16* __restrict__ wpf1) {
    int id = blockIdx.x * 256 + threadIdx.x;
    if (id < 1280) {
        int t = id >> 6, oc = id & 63;
        _Float16* dh = wph + (size_t)id * 32;
        for (int s = 0; s < 32; ++s) {
            int k = t * 32 + s;
            int pix = (k * 2731) >> 16;       // /24, exact for k<640
            int icr = k - pix * 24;
            float w = 0.f;
            if (pix < 25 && icr < 20 && oc < 50)
                w = w2[oc * 500 + icr * 25 + pix];
            dh[s] = (_Float16)w;
        }
    } else if (id < 1408) {
        int l = id - 1280;
        int lane = l & 63, tile = l >> 6;
        int rr = lane & 15, kg = lane >> 4;
        int oc = tile * 16 + rr;
        _Float16* dst = wpc1 + (size_t)l * 8;
        for (int j = 0; j < 8; ++j) {
            int t = kg * 8 + j;
            float w = (oc < 20 && t < 25) ? w1[oc * 25 + t] : 0.f;
            dst[j] = (_Float16)w;
        }
    } else if (id < 14208) {
        int id2 = id - 1408;
        int t = id2 >> 9, oc = id2 & 511;
        _Float16* dst = wpf1 + (size_t)id2 * 64;
        for (int kk = 0; kk < 32; ++kk) {
            float w = (oc < 500) ? wf1[(size_t)oc * 800 + t * 32 + kk] : 0.f;
            _Float16 hi = (_Float16)w;
            dst[kk] = hi;
            dst[32 + kk] = (_Float16)(w - (float)hi);
        }
    }
}

// ---------------------------------------------------------------------------
// K1: conv1 via MFMA 16x16x32_f16 + fused bias/trunc/relu/pool.
// ---------------------------------------------------------------------------
__global__ __launch_bounds__(256) void k_conv1(const float* __restrict__ x,
                                               const _Float16* __restrict__ wpc1,
                                               const float* __restrict__ b1,
                                               _Float16* __restrict__ p1h) {
    int tid = threadIdx.x;
    int wid = tid >> 6, lane = tid & 63;
    int b = blockIdx.x * 4 + wid;
    int kg = lane >> 4, rr = lane & 15;
    int py = rr >> 2, px = rr & 3;

    v8h bf0 = *(const v8h*)(wpc1 + (size_t)lane * 8);
    v8h bf1 = *(const v8h*)(wpc1 + (size_t)(64 + lane) * 8);
    float bias0 = b1[rr];
    float bias1 = (rr < 4) ? b1[16 + rr] : 0.f;

    int off[8];
#pragma unroll
    for (int j = 0; j < 8; ++j) {
        int t = kg * 8 + j;
        if (t > 24) t = 24;
        int ky = (t * 205) >> 10;
        int kx = t - 5 * ky;
        off[j] = (py + ky) * 28 + (px + kx);
    }

    const float* img = x + (size_t)b * 784;
    _Float16* outb = p1h + (size_t)b * 144 * 24;

    for (int qy = 0; qy < 6; ++qy) {
#pragma unroll
        for (int qx = 0; qx < 6; ++qx) {
            const float* base = img + (qy * 4) * 28 + qx * 4;
            v8h a;
#pragma unroll
            for (int j = 0; j < 8; ++j) a[j] = (_Float16)base[off[j]];

            v4f acc0 = {0.f, 0.f, 0.f, 0.f}, acc1 = {0.f, 0.f, 0.f, 0.f};
            acc0 = __builtin_amdgcn_mfma_f32_16x16x32_f16(a, bf0, acc0, 0, 0, 0);
            acc1 = __builtin_amdgcn_mfma_f32_16x16x32_f16(a, bf1, acc1, 0, 0, 0);

            float z0 = fmaxf(trunc13(acc0[0] + bias0), 0.f);
            float z1 = fmaxf(trunc13(acc0[1] + bias0), 0.f);
            float z2 = fmaxf(trunc13(acc0[2] + bias0), 0.f);
            float z3 = fmaxf(trunc13(acc0[3] + bias0), 0.f);
            float m01 = fmaxf(z0, z1), m23 = fmaxf(z2, z3);
            float p01 = fmaxf(m01, __shfl_xor(m01, 16, 64));
            float p23 = fmaxf(m23, __shfl_xor(m23, 16, 64));
            float y0 = fmaxf(trunc13(acc1[0] + bias1), 0.f);
            float y1 = fmaxf(trunc13(acc1[1] + bias1), 0.f);
            float y2 = fmaxf(trunc13(acc1[2] + bias1), 0.f);
            float y3 = fmaxf(trunc13(acc1[3] + bias1), 0.f);
            float n01 = fmaxf(y0, y1), n23 = fmaxf(y2, y3);
            float q01 = fmaxf(n01, __shfl_xor(n01, 16, 64));
            float q23 = fmaxf(n23, __shfl_xor(n23, 16, 64));

            if (!(kg & 1)) {
                int pos0 = (2 * qy + (kg >> 1)) * 12 + 2 * qx;
                _Float16* o = outb + (size_t)pos0 * 24;
                o[rr]      = (_Float16)p01;
                o[24 + rr] = (_Float16)p23;
                if (rr < 4) {
                    o[16 + rr]      = (_Float16)q01;
                    o[24 + 16 + rr] = (_Float16)q23;
                }
            }
        }
    }
}

// ---------------------------------------------------------------------------
// K2: conv2 via MFMA 16x16x32_f16, hi-only, 19 K-steps (t=19 was all-zero).
// Block = 8 images, 4 waves; wave = 2 images (my=8), nt=4.
// ---------------------------------------------------------------------------
#define AIMG3 3744   // 156 rows * 24 halfs (rows 144..155 zero pad)
__global__ __launch_bounds__(256, 2) void k_conv2(const _Float16* __restrict__ p1h,
                                                  const _Float16* __restrict__ wph,
                                                  const float* __restrict__ b2,
                                                  _Float16* __restrict__ p2h) {
    __shared__ __align__(16) _Float16 Al[8 * AIMG3];   // 59904 B
    int tid = threadIdx.x;
    int b0 = blockIdx.x * 8;

    {
        const uint4* src = (const uint4*)(p1h + (size_t)b0 * 3456);
        uint4* dst = (uint4*)Al;
        uint4 z = make_uint4(0u, 0u, 0u, 0u);
        for (int i = tid; i < 3744; i += 256) {
            int img = i / 468, r = i - img * 468;
            dst[i] = (r < 432) ? src[img * 432 + r] : z;
        }
    }
    __syncthreads();

    int wid = tid >> 6, lane = tid & 63;
    int kg = lane >> 4, rr = lane & 15;
    int Y = rr >> 3, xx = rr & 7;
    const _Float16* Ab0 = Al + (wid * 2) * AIMG3;
    const _Float16* Ab1 = Ab0 + AIMG3;
    const _Float16* abase[8];
#pragma unroll
    for (int my = 0; my < 4; ++my) {
        abase[my]     = Ab0 + ((2 * my + Y) * 12 + xx) * 24;
        abase[my + 4] = Ab1 + ((2 * my + Y) * 12 + xx) * 24;
    }
    const _Float16* bh_base = wph + rr * 32 + kg * 8;

    v4f acc[8][4];
#pragma unroll
    for (int my = 0; my < 8; ++my)
#pragma unroll
        for (int nt = 0; nt < 4; ++nt) acc[my][nt] = (v4f){0.f, 0.f, 0.f, 0.f};

#define CSTEP(T, BV)                                                          \
    {                                                                         \
        int k0 = (T) * 32 + kg * 8;                                           \
        int pix = (k0 * 2731) >> 16;                                          \
        int icol = k0 - pix * 24;                                             \
        int ky = (pix * 205) >> 10;                                           \
        int kx = pix - 5 * ky;                                                \
        int aofs = (ky * 12 + kx) * 24 + icol;                                \
        v8h af[8];                                                            \
        _Pragma("unroll")                                                     \
        for (int my = 0; my < 8; ++my)                                        \
            af[my] = *(const v8h*)(abase[my] + aofs);                         \
        _Pragma("unroll")                                                     \
        for (int my = 0; my < 8; ++my)                                        \
            _Pragma("unroll")                                                 \
            for (int nt = 0; nt < 4; ++nt)                                    \
                acc[my][nt] = __builtin_amdgcn_mfma_f32_16x16x32_f16(         \
                    af[my], BV[nt], acc[my][nt], 0, 0, 0);                    \
    }

    for (int u = 0; u < 9; ++u) {
        int t0 = 2 * u, t1 = 2 * u + 1;
        v8h bA[4], bB[4];
#pragma unroll
        for (int nt = 0; nt < 4; ++nt) {
            bA[nt] = *(const v8h*)(bh_base + t0 * 2048 + nt * 512);
            bB[nt] = *(const v8h*)(bh_base + t1 * 2048 + nt * 512);
        }
        CSTEP(t0, bA);
        CSTEP(t1, bB);
    }
    {   // tail step t=18
        v8h bA[4];
#pragma unroll
        for (int nt = 0; nt < 4; ++nt)
            bA[nt] = *(const v8h*)(bh_base + 18 * 2048 + nt * 512);
        CSTEP(18, bA);
    }
#undef CSTEP

#pragma unroll
    for (int h = 0; h < 2; ++h) {
        int imgg = b0 + wid * 2 + h;
#pragma unroll
        for (int nt = 0; nt < 4; ++nt) {
            int oc = nt * 16 + rr;
            float bias = (oc < 50) ? b2[oc] : 0.f;
#pragma unroll
            for (int my = 0; my < 4; ++my) {
                v4f a = acc[h * 4 + my][nt];
                float z0 = fmaxf(trunc13(a[0] + bias), 0.f);
                float z1 = fmaxf(trunc13(a[1] + bias), 0.f);
                float z2 = fmaxf(trunc13(a[2] + bias), 0.f);
                float z3 = fmaxf(trunc13(a[3] + bias), 0.f);
                float s0 = fmaxf(z0, z1), s2 = fmaxf(z2, z3);
                float o0 = fmaxf(s0, __shfl_xor(s0, 32, 64));
                float o2 = fmaxf(s2, __shfl_xor(s2, 32, 64));
                if (kg < 2 && oc < 50) {
                    p2h[(size_t)imgg * 800 + oc * 16 + my * 4 + 2 * kg]     = (_Float16)o0;
                    p2h[(size_t)imgg * 800 + oc * 16 + my * 4 + 2 * kg + 1] = (_Float16)o2;
                }
            }
        }
    }
}

// ---------------------------------------------------------------------------
// K3: fc1 via MFMA 16x16x32_f16, hi-only, LDS-FREE & barrier-free.
// Each wave's A and B fragments are consumed once -> staging protected no
// reuse (B cross-wave reuse costs only ~104MB L2 ~ 3us). A,B from L2;
// TLP (8 waves/SIMD at ~80 VGPR) hides latency. Bit-identical arithmetic.
// BM=128 BN=64, grid 32x8, 4 waves (wave = 32 rows, mf=2, nf=4).
// ---------------------------------------------------------------------------
__global__ __launch_bounds__(256) void k_fc1(const _Float16* __restrict__ Ah,
                                             const _Float16* __restrict__ Bp,
                                             const float* __restrict__ bias,
                                             _Float16* __restrict__ Hh) {
    int tid = threadIdx.x;
    int i0 = blockIdx.x * 128, n0 = blockIdx.y * 64;
    int wid = tid >> 6, lane = tid & 63;
    int rr = lane & 15, kg = lane >> 4;

    const _Float16* arow[2];
#pragma unroll
    for (int mf = 0; mf < 2; ++mf)
        arow[mf] = Ah + (size_t)(i0 + wid * 32 + mf * 16 + rr) * 800 + kg * 8;
    const _Float16* brow[4];
#pragma unroll
    for (int nf = 0; nf < 4; ++nf)
        brow[nf] = Bp + (size_t)(n0 + nf * 16 + rr) * 64 + kg * 8;

    v4f acc[2][4];
#pragma unroll
    for (int mf = 0; mf < 2; ++mf)
#pragma unroll
        for (int nf = 0; nf < 4; ++nf) acc[mf][nf] = (v4f){0.f, 0.f, 0.f, 0.f};

    for (int t = 0; t < 25; ++t) {
        v8h af[2], bh[4];
#pragma unroll
        for (int mf = 0; mf < 2; ++mf)
            af[mf] = *(const v8h*)(arow[mf] + t * 32);
#pragma unroll
        for (int nf = 0; nf < 4; ++nf)
            bh[nf] = *(const v8h*)(brow[nf] + (size_t)t * 32768);
#pragma unroll
        for (int mf = 0; mf < 2; ++mf)
#pragma unroll
            for (int nf = 0; nf < 4; ++nf)
                acc[mf][nf] = __builtin_amdgcn_mfma_f32_16x16x32_f16(af[mf], bh[nf], acc[mf][nf], 0, 0, 0);
    }

#pragma unroll
    for (int mf = 0; mf < 2; ++mf)
#pragma unroll
        for (int nf = 0; nf < 4; ++nf) {
            int col = n0 + nf * 16 + rr;
            float bs = bias[col < 500 ? col : 0];
#pragma unroll
            for (int j = 0; j < 4; ++j) {
                int row = i0 + wid * 32 + mf * 16 + kg * 4 + j;
                float v = fmaxf(trunc13(acc[mf][nf][j] + bs), 0.f);
                if (col < 500) Hh[(size_t)row * 512 + col] = (_Float16)v;
            }
        }
}

// ---------------------------------------------------------------------------
// K4: fc2 (500->10) + bias + trunc + log_softmax.  One wave per row, fp16 H.
// ---------------------------------------------------------------------------
__global__ __launch_bounds__(256) void k_fc2(const _Float16* __restrict__ Hh,
                                             const float* __restrict__ W,
                                             const float* __restrict__ bias,
                                             float* __restrict__ out) {
    int wave = threadIdx.x >> 6;
    int lane = threadIdx.x & 63;
    int i = blockIdx.x * 4 + wave;
    const _Float16* hrow = Hh + (size_t)i * 512;

    float p[10];
#pragma unroll
    for (int j = 0; j < 10; ++j) p[j] = 0.f;
    for (int k = lane; k < 500; k += 64) {
        float h = (float)hrow[k];
#pragma unroll
        for (int j = 0; j < 10; ++j) p[j] += h * W[j * 500 + k];
    }
#pragma unroll
    for (int j = 0; j < 10; ++j)
#pragma unroll
        for (int off = 32; off; off >>= 1) p[j] += __shfl_xor(p[j], off, 64);

    if (lane == 0) {
        float z[10], m = -1e30f;
#pragma unroll
        for (int j = 0; j < 10; ++j) {
            z[j] = trunc13(p[j] + bias[j]);
            m = fmaxf(m, z[j]);
        }
        float s = 0.f;
#pragma unroll
        for (int j = 0; j < 10; ++j) s += expf(z[j] - m);
        float lse = m + logf(s);
#pragma unroll
        for (int j = 0; j < 10; ++j) out[(size_t)i * 10 + j] = z[j] - lse;
    }
}

// ---------------------------------------------------------------------------
extern "C" void kernel_launch(void* const* d_in, const int* in_sizes, int n_in,
                              void* d_out, int out_size, void* d_ws, size_t ws_size,
                              hipStream_t stream) {
    const float* x   = (const float*)d_in[0];
    const float* w1  = (const float*)d_in[1];
    const float* b1  = (const float*)d_in[2];
    const float* w2  = (const float*)d_in[3];
    const float* b2  = (const float*)d_in[4];
    const float* wf1 = (const float*)d_in[5];
    const float* bf1 = (const float*)d_in[6];
    const float* wf2 = (const float*)d_in[7];
    const float* bf2 = (const float*)d_in[8];
    float* out = (float*)d_out;

    char* ws = (char*)d_ws;
    _Float16* p1h  = (_Float16*)(ws);                   // 28,311,552
    _Float16* p2h  = (_Float16*)(ws + 28311552);        //  6,553,600
    _Float16* h1h  = (_Float16*)(ws + 34865152);        //  4,194,304
    _Float16* wph  = (_Float16*)(ws + 39059456);        //     81,920
    _Float16* wpf1 = (_Float16*)(ws + 39141376);        //  1,638,400
    _Float16* wpc1 = (_Float16*)(ws + 40779776);        //      2,048

    k_prep<<<56, 256, 0, stream>>>(w1, w2, wf1, wpc1, wph, wpf1);
    k_conv1<<<1024, 256, 0, stream>>>(x, wpc1, b1, p1h);
    k_conv2<<<512, 256, 0, stream>>>(p1h, wph, b2, p2h);
    dim3 g3(32, 8);
    k_fc1<<<g3, 256, 0, stream>>>(p2h, wpf1, bf1, h1h);
    k_fc2<<<1024, 256, 0, stream>>>(h1h, wf2, bf2, out);
}

// Round 25
// 96.608 us; speedup vs baseline: 1.0403x; 1.0403x over previous
//
#include <hip/hip_runtime.h>

// LeNet forward, BATCH=4096. trunc = zero low 13 bits of fp32 mantissa.
// ALL layers via fp16 MFMA, hi-plane weights only (absmax stable 0.0156).
// conv1: 1 K-step MFMA + in-register pool. conv2: 19 K-steps, B from L2,
// 64-MFMA bursts wrapped in s_setprio (waves drift out of phase -> T5 pays).
// fc1: LDS+swizzle dbuf version (R20-measured-good; LDS-free regressed).
// ws layout (bytes):
//   p1h  [4096][144][24] fp16 @ 0            (28,311,552)
//   p2h  [4096][800]     fp16 @ 28,311,552   ( 6,553,600)
//   h1h  [4096][512]     fp16 @ 34,865,152   ( 4,194,304)
//   wph  [20][64][32]    fp16 @ 39,059,456   (    81,920)
//   wpf1 [25][512][64]   fp16 @ 39,141,376   ( 1,638,400)
//   wpc1 [2][64][8]      fp16 @ 40,779,776   (     2,048)

typedef _Float16 v8h __attribute__((ext_vector_type(8)));
typedef float v4f __attribute__((ext_vector_type(4)));

__device__ __forceinline__ float trunc13(float v) {
    return __int_as_float(__float_as_int(v) & (int)0xFFFFE000u);
}

// ---------------------------------------------------------------------------
// K0: ALL weight prep in one kernel.
// ---------------------------------------------------------------------------
__global__ void k_prep(const float* __restrict__ w1, const float* __restrict__ w2,
                       const float* __restrict__ wf1,
                       _Float16* __restrict__ wpc1, _Float16* __restrict__ wph,
                       _Float16* __restrict__ wpf1) {
    int id = blockIdx.x * 256 + threadIdx.x;
    if (id < 1280) {
        int t = id >> 6, oc = id & 63;
        _Float16* dh = wph + (size_t)id * 32;
        for (int s = 0; s < 32; ++s) {
            int k = t * 32 + s;
            int pix = (k * 2731) >> 16;       // /24, exact for k<640
            int icr = k - pix * 24;
            float w = 0.f;
            if (pix < 25 && icr < 20 && oc < 50)
                w = w2[oc * 500 + icr * 25 + pix];
            dh[s] = (_Float16)w;
        }
    } else if (id < 1408) {
        int l = id - 1280;
        int lane = l & 63, tile = l >> 6;
        int rr = lane & 15, kg = lane >> 4;
        int oc = tile * 16 + rr;
        _Float16* dst = wpc1 + (size_t)l * 8;
        for (int j = 0; j < 8; ++j) {
            int t = kg * 8 + j;
            float w = (oc < 20 && t < 25) ? w1[oc * 25 + t] : 0.f;
            dst[j] = (_Float16)w;
        }
    } else if (id < 14208) {
        int id2 = id - 1408;
        int t = id2 >> 9, oc = id2 & 511;
        _Float16* dst = wpf1 + (size_t)id2 * 64;
        for (int kk = 0; kk < 32; ++kk) {
            float w = (oc < 500) ? wf1[(size_t)oc * 800 + t * 32 + kk] : 0.f;
            _Float16 hi = (_Float16)w;
            dst[kk] = hi;
            dst[32 + kk] = (_Float16)(w - (float)hi);
        }
    }
}

// ---------------------------------------------------------------------------
// K1: conv1 via MFMA 16x16x32_f16 + fused bias/trunc/relu/pool.
// ---------------------------------------------------------------------------
__global__ __launch_bounds__(256) void k_conv1(const float* __restrict__ x,
                                               const _Float16* __restrict__ wpc1,
                                               const float* __restrict__ b1,
                                               _Float16* __restrict__ p1h) {
    int tid = threadIdx.x;
    int wid = tid >> 6, lane = tid & 63;
    int b = blockIdx.x * 4 + wid;
    int kg = lane >> 4, rr = lane & 15;
    int py = rr >> 2, px = rr & 3;

    v8h bf0 = *(const v8h*)(wpc1 + (size_t)lane * 8);
    v8h bf1 = *(const v8h*)(wpc1 + (size_t)(64 + lane) * 8);
    float bias0 = b1[rr];
    float bias1 = (rr < 4) ? b1[16 + rr] : 0.f;

    int off[8];
#pragma unroll
    for (int j = 0; j < 8; ++j) {
        int t = kg * 8 + j;
        if (t > 24) t = 24;
        int ky = (t * 205) >> 10;
        int kx = t - 5 * ky;
        off[j] = (py + ky) * 28 + (px + kx);
    }

    const float* img = x + (size_t)b * 784;
    _Float16* outb = p1h + (size_t)b * 144 * 24;

    for (int qy = 0; qy < 6; ++qy) {
#pragma unroll
        for (int qx = 0; qx < 6; ++qx) {
            const float* base = img + (qy * 4) * 28 + qx * 4;
            v8h a;
#pragma unroll
            for (int j = 0; j < 8; ++j) a[j] = (_Float16)base[off[j]];

            v4f acc0 = {0.f, 0.f, 0.f, 0.f}, acc1 = {0.f, 0.f, 0.f, 0.f};
            acc0 = __builtin_amdgcn_mfma_f32_16x16x32_f16(a, bf0, acc0, 0, 0, 0);
            acc1 = __builtin_amdgcn_mfma_f32_16x16x32_f16(a, bf1, acc1, 0, 0, 0);

            float z0 = fmaxf(trunc13(acc0[0] + bias0), 0.f);
            float z1 = fmaxf(trunc13(acc0[1] + bias0), 0.f);
            float z2 = fmaxf(trunc13(acc0[2] + bias0), 0.f);
            float z3 = fmaxf(trunc13(acc0[3] + bias0), 0.f);
            float m01 = fmaxf(z0, z1), m23 = fmaxf(z2, z3);
            float p01 = fmaxf(m01, __shfl_xor(m01, 16, 64));
            float p23 = fmaxf(m23, __shfl_xor(m23, 16, 64));
            float y0 = fmaxf(trunc13(acc1[0] + bias1), 0.f);
            float y1 = fmaxf(trunc13(acc1[1] + bias1), 0.f);
            float y2 = fmaxf(trunc13(acc1[2] + bias1), 0.f);
            float y3 = fmaxf(trunc13(acc1[3] + bias1), 0.f);
            float n01 = fmaxf(y0, y1), n23 = fmaxf(y2, y3);
            float q01 = fmaxf(n01, __shfl_xor(n01, 16, 64));
            float q23 = fmaxf(n23, __shfl_xor(n23, 16, 64));

            if (!(kg & 1)) {
                int pos0 = (2 * qy + (kg >> 1)) * 12 + 2 * qx;
                _Float16* o = outb + (size_t)pos0 * 24;
                o[rr]      = (_Float16)p01;
                o[24 + rr] = (_Float16)p23;
                if (rr < 4) {
                    o[16 + rr]      = (_Float16)q01;
                    o[24 + 16 + rr] = (_Float16)q23;
                }
            }
        }
    }
}

// ---------------------------------------------------------------------------
// K2: conv2 via MFMA 16x16x32_f16, hi-only, 19 K-steps, setprio-wrapped
// bursts. Block = 8 images, 4 waves; wave = 2 images (my=8), nt=4.
// ---------------------------------------------------------------------------
#define AIMG3 3744   // 156 rows * 24 halfs (rows 144..155 zero pad)
__global__ __launch_bounds__(256, 2) void k_conv2(const _Float16* __restrict__ p1h,
                                                  const _Float16* __restrict__ wph,
                                                  const float* __restrict__ b2,
                                                  _Float16* __restrict__ p2h) {
    __shared__ __align__(16) _Float16 Al[8 * AIMG3];   // 59904 B
    int tid = threadIdx.x;
    int b0 = blockIdx.x * 8;

    {
        const uint4* src = (const uint4*)(p1h + (size_t)b0 * 3456);
        uint4* dst = (uint4*)Al;
        uint4 z = make_uint4(0u, 0u, 0u, 0u);
        for (int i = tid; i < 3744; i += 256) {
            int img = i / 468, r = i - img * 468;
            dst[i] = (r < 432) ? src[img * 432 + r] : z;
        }
    }
    __syncthreads();

    int wid = tid >> 6, lane = tid & 63;
    int kg = lane >> 4, rr = lane & 15;
    int Y = rr >> 3, xx = rr & 7;
    const _Float16* Ab0 = Al + (wid * 2) * AIMG3;
    const _Float16* Ab1 = Ab0 + AIMG3;
    const _Float16* abase[8];
#pragma unroll
    for (int my = 0; my < 4; ++my) {
        abase[my]     = Ab0 + ((2 * my + Y) * 12 + xx) * 24;
        abase[my + 4] = Ab1 + ((2 * my + Y) * 12 + xx) * 24;
    }
    const _Float16* bh_base = wph + rr * 32 + kg * 8;

    v4f acc[8][4];
#pragma unroll
    for (int my = 0; my < 8; ++my)
#pragma unroll
        for (int nt = 0; nt < 4; ++nt) acc[my][nt] = (v4f){0.f, 0.f, 0.f, 0.f};

#define CSTEP(T, BV)                                                          \
    {                                                                         \
        int k0 = (T) * 32 + kg * 8;                                           \
        int pix = (k0 * 2731) >> 16;                                          \
        int icol = k0 - pix * 24;                                             \
        int ky = (pix * 205) >> 10;                                           \
        int kx = pix - 5 * ky;                                                \
        int aofs = (ky * 12 + kx) * 24 + icol;                                \
        v8h af[8];                                                            \
        _Pragma("unroll")                                                     \
        for (int my = 0; my < 8; ++my)                                        \
            af[my] = *(const v8h*)(abase[my] + aofs);                         \
        __builtin_amdgcn_s_setprio(1);                                        \
        _Pragma("unroll")                                                     \
        for (int my = 0; my < 8; ++my)                                        \
            _Pragma("unroll")                                                 \
            for (int nt = 0; nt < 4; ++nt)                                    \
                acc[my][nt] = __builtin_amdgcn_mfma_f32_16x16x32_f16(         \
                    af[my], BV[nt], acc[my][nt], 0, 0, 0);                    \
        __builtin_amdgcn_s_setprio(0);                                        \
    }

    for (int u = 0; u < 9; ++u) {
        int t0 = 2 * u, t1 = 2 * u + 1;
        v8h bA[4], bB[4];
#pragma unroll
        for (int nt = 0; nt < 4; ++nt) {
            bA[nt] = *(const v8h*)(bh_base + t0 * 2048 + nt * 512);
            bB[nt] = *(const v8h*)(bh_base + t1 * 2048 + nt * 512);
        }
        CSTEP(t0, bA);
        CSTEP(t1, bB);
    }
    {   // tail step t=18
        v8h bA[4];
#pragma unroll
        for (int nt = 0; nt < 4; ++nt)
            bA[nt] = *(const v8h*)(bh_base + 18 * 2048 + nt * 512);
        CSTEP(18, bA);
    }
#undef CSTEP

#pragma unroll
    for (int h = 0; h < 2; ++h) {
        int imgg = b0 + wid * 2 + h;
#pragma unroll
        for (int nt = 0; nt < 4; ++nt) {
            int oc = nt * 16 + rr;
            float bias = (oc < 50) ? b2[oc] : 0.f;
#pragma unroll
            for (int my = 0; my < 4; ++my) {
                v4f a = acc[h * 4 + my][nt];
                float z0 = fmaxf(trunc13(a[0] + bias), 0.f);
                float z1 = fmaxf(trunc13(a[1] + bias), 0.f);
                float z2 = fmaxf(trunc13(a[2] + bias), 0.f);
                float z3 = fmaxf(trunc13(a[3] + bias), 0.f);
                float s0 = fmaxf(z0, z1), s2 = fmaxf(z2, z3);
                float o0 = fmaxf(s0, __shfl_xor(s0, 32, 64));
                float o2 = fmaxf(s2, __shfl_xor(s2, 32, 64));
                if (kg < 2 && oc < 50) {
                    p2h[(size_t)imgg * 800 + oc * 16 + my * 4 + 2 * kg]     = (_Float16)o0;
                    p2h[(size_t)imgg * 800 + oc * 16 + my * 4 + 2 * kg + 1] = (_Float16)o2;
                }
            }
        }
    }
}

// ---------------------------------------------------------------------------
// K3: fc1 via MFMA 16x16x32_f16, hi-only. BM=128 BN=64 BK=32, grid 32x8,
// 4 waves; A XOR-swizzled, B stride-5-granule (conflict-free); T14 dbuf.
// (R20-measured-good version; LDS-free variant regressed in R21.)
// ---------------------------------------------------------------------------
__global__ __launch_bounds__(256) void k_fc1(const _Float16* __restrict__ Ah,
                                             const _Float16* __restrict__ Bp,
                                             const float* __restrict__ bias,
                                             _Float16* __restrict__ Hh) {
    __shared__ _Float16 Al[2][4096];
    __shared__ _Float16 Bl[2][2560];
    int tid = threadIdx.x;
    int i0 = blockIdx.x * 128, n0 = blockIdx.y * 64;
    int wid = tid >> 6, lane = tid & 63;
    int rr = lane & 15, kg = lane >> 4;

    int ca0 = tid, ca1 = tid + 256;
    int ra0_ = ca0 >> 2, qa0 = ca0 & 3, ra1_ = ca1 >> 2, qa1 = ca1 & 3;
    int aw0 = (ra0_ * 4 + (qa0 ^ ((ra0_ >> 1) & 3))) * 8;
    int aw1 = (ra1_ * 4 + (qa1 ^ ((ra1_ >> 1) & 3))) * 8;
    int bwB = ((tid >> 2) * 5 + (tid & 3)) * 8;

    uint4 xa0, xa1, xb0;
    auto loadT = [&](int t) {
        xa0 = *(const uint4*)(Ah + (size_t)(i0 + ra0_) * 800 + t * 32 + qa0 * 8);
        xa1 = *(const uint4*)(Ah + (size_t)(i0 + ra1_) * 800 + t * 32 + qa1 * 8);
        const uint4* g = (const uint4*)Bp + (size_t)t * 4096 + (size_t)n0 * 8;
        xb0 = g[(tid >> 2) * 8 + (tid & 3)];
    };
    auto writeT = [&](int buf) {
        *(uint4*)(&Al[buf][aw0]) = xa0;
        *(uint4*)(&Al[buf][aw1]) = xa1;
        *(uint4*)(&Bl[buf][bwB]) = xb0;
    };

    int aoff[2], bhoff[4];
#pragma unroll
    for (int mf = 0; mf < 2; ++mf) {
        int r = wid * 32 + mf * 16 + rr;
        aoff[mf] = (r * 4 + (kg ^ ((rr >> 1) & 3))) * 8;
    }
#pragma unroll
    for (int nf = 0; nf < 4; ++nf)
        bhoff[nf] = ((nf * 16 + rr) * 5 + kg) * 8;

    v4f zero = {0.f, 0.f, 0.f, 0.f};
    v4f acc[2][4];
#pragma unroll
    for (int mf = 0; mf < 2; ++mf)
#pragma unroll
        for (int nf = 0; nf < 4; ++nf) acc[mf][nf] = zero;

    loadT(0);
    writeT(0);
    __syncthreads();

    for (int t = 0; t < 25; ++t) {
        int cur = t & 1;
        if (t < 24) loadT(t + 1);
        v8h af[2], bh[4];
#pragma unroll
        for (int mf = 0; mf < 2; ++mf) af[mf] = *(const v8h*)(&Al[cur][aoff[mf]]);
#pragma unroll
        for (int nf = 0; nf < 4; ++nf) bh[nf] = *(const v8h*)(&Bl[cur][bhoff[nf]]);
#pragma unroll
        for (int mf = 0; mf < 2; ++mf)
#pragma unroll
            for (int nf = 0; nf < 4; ++nf)
                acc[mf][nf] = __builtin_amdgcn_mfma_f32_16x16x32_f16(af[mf], bh[nf], acc[mf][nf], 0, 0, 0);
        if (t < 24) writeT(cur ^ 1);
        __syncthreads();
    }

#pragma unroll
    for (int mf = 0; mf < 2; ++mf)
#pragma unroll
        for (int nf = 0; nf < 4; ++nf) {
            int col = n0 + nf * 16 + rr;
            float bs = bias[col < 500 ? col : 0];
#pragma unroll
            for (int j = 0; j < 4; ++j) {
                int row = i0 + wid * 32 + mf * 16 + kg * 4 + j;
                float v = fmaxf(trunc13(acc[mf][nf][j] + bs), 0.f);
                if (col < 500) Hh[(size_t)row * 512 + col] = (_Float16)v;
            }
        }
}

// ---------------------------------------------------------------------------
// K4: fc2 (500->10) + bias + trunc + log_softmax.  One wave per row, fp16 H.
// ---------------------------------------------------------------------------
__global__ __launch_bounds__(256) void k_fc2(const _Float16* __restrict__ Hh,
                                             const float* __restrict__ W,
                                             const float* __restrict__ bias,
                                             float* __restrict__ out) {
    int wave = threadIdx.x >> 6;
    int lane = threadIdx.x & 63;
    int i = blockIdx.x * 4 + wave;
    const _Float16* hrow = Hh + (size_t)i * 512;

    float p[10];
#pragma unroll
    for (int j = 0; j < 10; ++j) p[j] = 0.f;
    for (int k = lane; k < 500; k += 64) {
        float h = (float)hrow[k];
#pragma unroll
        for (int j = 0; j < 10; ++j) p[j] += h * W[j * 500 + k];
    }
#pragma unroll
    for (int j = 0; j < 10; ++j)
#pragma unroll
        for (int off = 32; off; off >>= 1) p[j] += __shfl_xor(p[j], off, 64);

    if (lane == 0) {
        float z[10], m = -1e30f;
#pragma unroll
        for (int j = 0; j < 10; ++j) {
            z[j] = trunc13(p[j] + bias[j]);
            m = fmaxf(m, z[j]);
        }
        float s = 0.f;
#pragma unroll
        for (int j = 0; j < 10; ++j) s += expf(z[j] - m);
        float lse = m + logf(s);
#pragma unroll
        for (int j = 0; j < 10; ++j) out[(size_t)i * 10 + j] = z[j] - lse;
    }
}

// ---------------------------------------------------------------------------
extern "C" void kernel_launch(void* const* d_in, const int* in_sizes, int n_in,
                              void* d_out, int out_size, void* d_ws, size_t ws_size,
                              hipStream_t stream) {
    const float* x   = (const float*)d_in[0];
    const float* w1  = (const float*)d_in[1];
    const float* b1  = (const float*)d_in[2];
    const float* w2  = (const float*)d_in[3];
    const float* b2  = (const float*)d_in[4];
    const float* wf1 = (const float*)d_in[5];
    const float* bf1 = (const float*)d_in[6];
    const float* wf2 = (const float*)d_in[7];
    const float* bf2 = (const float*)d_in[8];
    float* out = (float*)d_out;

    char* ws = (char*)d_ws;
    _Float16* p1h  = (_Float16*)(ws);                   // 28,311,552
    _Float16* p2h  = (_Float16*)(ws + 28311552);        //  6,553,600
    _Float16* h1h  = (_Float16*)(ws + 34865152);        //  4,194,304
    _Float16* wph  = (_Float16*)(ws + 39059456);        //     81,920
    _Float16* wpf1 = (_Float16*)(ws + 39141376);        //  1,638,400
    _Float16* wpc1 = (_Float16*)(ws + 40779776);        //      2,048

    k_prep<<<56, 256, 0, stream>>>(w1, w2, wf1, wpc1, wph, wpf1);
    k_conv1<<<1024, 256, 0, stream>>>(x, wpc1, b1, p1h);
    k_conv2<<<512, 256, 0, stream>>>(p1h, wph, b2, p2h);
    dim3 g3(32, 8);
    k_fc1<<<g3, 256, 0, stream>>>(p2h, wpf1, bf1, h1h);
    k_fc2<<<1024, 256, 0, stream>>>(h1h, wf2, bf2, out);
}

// Round 26
// 96.508 us; speedup vs baseline: 1.0413x; 1.0010x over previous
//
#include <hip/hip_runtime.h>

// LeNet forward, BATCH=4096. trunc = zero low 13 bits of fp32 mantissa.
// ALL layers via fp16 MFMA, hi-plane weights only (absmax stable 0.0156).
// conv1: 1 K-step MFMA + in-register pool. conv2: 19 K-steps, B from L2,
// MERGED 64-MFMA bursts (2 K-steps per setprio region, ~310cyc > L2 lat).
// fc1: LDS+swizzle dbuf (measured-good). fc2: wave/row dot.
// ws layout (bytes):
//   p1h  [4096][144][24] fp16 @ 0            (28,311,552)
//   p2h  [4096][800]     fp16 @ 28,311,552   ( 6,553,600)
//   h1h  [4096][512]     fp16 @ 34,865,152   ( 4,194,304)
//   wph  [20][64][32]    fp16 @ 39,059,456   (    81,920)
//   wpf1 [25][512][64]   fp16 @ 39,141,376   ( 1,638,400)
//   wpc1 [2][64][8]      fp16 @ 40,779,776   (     2,048)

typedef _Float16 v8h __attribute__((ext_vector_type(8)));
typedef float v4f __attribute__((ext_vector_type(4)));

__device__ __forceinline__ float trunc13(float v) {
    return __int_as_float(__float_as_int(v) & (int)0xFFFFE000u);
}

// ---------------------------------------------------------------------------
// K0: ALL weight prep in one kernel.
// ---------------------------------------------------------------------------
__global__ void k_prep(const float* __restrict__ w1, const float* __restrict__ w2,
                       const float* __restrict__ wf1,
                       _Float16* __restrict__ wpc1, _Float16* __restrict__ wph,
                       _Float16* __restrict__ wpf1) {
    int id = blockIdx.x * 256 + threadIdx.x;
    if (id < 1280) {
        int t = id >> 6, oc = id & 63;
        _Float16* dh = wph + (size_t)id * 32;
        for (int s = 0; s < 32; ++s) {
            int k = t * 32 + s;
            int pix = (k * 2731) >> 16;       // /24, exact for k<640
            int icr = k - pix * 24;
            float w = 0.f;
            if (pix < 25 && icr < 20 && oc < 50)
                w = w2[oc * 500 + icr * 25 + pix];
            dh[s] = (_Float16)w;
        }
    } else if (id < 1408) {
        int l = id - 1280;
        int lane = l & 63, tile = l >> 6;
        int rr = lane & 15, kg = lane >> 4;
        int oc = tile * 16 + rr;
        _Float16* dst = wpc1 + (size_t)l * 8;
        for (int j = 0; j < 8; ++j) {
            int t = kg * 8 + j;
            float w = (oc < 20 && t < 25) ? w1[oc * 25 + t] : 0.f;
            dst[j] = (_Float16)w;
        }
    } else if (id < 14208) {
        int id2 = id - 1408;
        int t = id2 >> 9, oc = id2 & 511;
        _Float16* dst = wpf1 + (size_t)id2 * 64;
        for (int kk = 0; kk < 32; ++kk) {
            float w = (oc < 500) ? wf1[(size_t)oc * 800 + t * 32 + kk] : 0.f;
            _Float16 hi = (_Float16)w;
            dst[kk] = hi;
            dst[32 + kk] = (_Float16)(w - (float)hi);
        }
    }
}

// ---------------------------------------------------------------------------
// K1: conv1 via MFMA 16x16x32_f16 + fused bias/trunc/relu/pool.
// ---------------------------------------------------------------------------
__global__ __launch_bounds__(256) void k_conv1(const float* __restrict__ x,
                                               const _Float16* __restrict__ wpc1,
                                               const float* __restrict__ b1,
                                               _Float16* __restrict__ p1h) {
    int tid = threadIdx.x;
    int wid = tid >> 6, lane = tid & 63;
    int b = blockIdx.x * 4 + wid;
    int kg = lane >> 4, rr = lane & 15;
    int py = rr >> 2, px = rr & 3;

    v8h bf0 = *(const v8h*)(wpc1 + (size_t)lane * 8);
    v8h bf1 = *(const v8h*)(wpc1 + (size_t)(64 + lane) * 8);
    float bias0 = b1[rr];
    float bias1 = (rr < 4) ? b1[16 + rr] : 0.f;

    int off[8];
#pragma unroll
    for (int j = 0; j < 8; ++j) {
        int t = kg * 8 + j;
        if (t > 24) t = 24;
        int ky = (t * 205) >> 10;
        int kx = t - 5 * ky;
        off[j] = (py + ky) * 28 + (px + kx);
    }

    const float* img = x + (size_t)b * 784;
    _Float16* outb = p1h + (size_t)b * 144 * 24;

    for (int qy = 0; qy < 6; ++qy) {
#pragma unroll
        for (int qx = 0; qx < 6; ++qx) {
            const float* base = img + (qy * 4) * 28 + qx * 4;
            v8h a;
#pragma unroll
            for (int j = 0; j < 8; ++j) a[j] = (_Float16)base[off[j]];

            v4f acc0 = {0.f, 0.f, 0.f, 0.f}, acc1 = {0.f, 0.f, 0.f, 0.f};
            acc0 = __builtin_amdgcn_mfma_f32_16x16x32_f16(a, bf0, acc0, 0, 0, 0);
            acc1 = __builtin_amdgcn_mfma_f32_16x16x32_f16(a, bf1, acc1, 0, 0, 0);

            float z0 = fmaxf(trunc13(acc0[0] + bias0), 0.f);
            float z1 = fmaxf(trunc13(acc0[1] + bias0), 0.f);
            float z2 = fmaxf(trunc13(acc0[2] + bias0), 0.f);
            float z3 = fmaxf(trunc13(acc0[3] + bias0), 0.f);
            float m01 = fmaxf(z0, z1), m23 = fmaxf(z2, z3);
            float p01 = fmaxf(m01, __shfl_xor(m01, 16, 64));
            float p23 = fmaxf(m23, __shfl_xor(m23, 16, 64));
            float y0 = fmaxf(trunc13(acc1[0] + bias1), 0.f);
            float y1 = fmaxf(trunc13(acc1[1] + bias1), 0.f);
            float y2 = fmaxf(trunc13(acc1[2] + bias1), 0.f);
            float y3 = fmaxf(trunc13(acc1[3] + bias1), 0.f);
            float n01 = fmaxf(y0, y1), n23 = fmaxf(y2, y3);
            float q01 = fmaxf(n01, __shfl_xor(n01, 16, 64));
            float q23 = fmaxf(n23, __shfl_xor(n23, 16, 64));

            if (!(kg & 1)) {
                int pos0 = (2 * qy + (kg >> 1)) * 12 + 2 * qx;
                _Float16* o = outb + (size_t)pos0 * 24;
                o[rr]      = (_Float16)p01;
                o[24 + rr] = (_Float16)p23;
                if (rr < 4) {
                    o[16 + rr]      = (_Float16)q01;
                    o[24 + 16 + rr] = (_Float16)q23;
                }
            }
        }
    }
}

// ---------------------------------------------------------------------------
// K2: conv2 via MFMA 16x16x32_f16, hi-only, 19 K-steps. Block = 8 images,
// 4 waves; wave = 2 images (my=8), nt=4. MERGED iteration: all loads for
// t0 AND t1 (8 global B + 16 ds_read A) before ONE setprio-wrapped
// 64-MFMA region (~310 cyc > ~250 cyc L2 latency).
// ---------------------------------------------------------------------------
#define AIMG3 3744   // 156 rows * 24 halfs (rows 144..155 zero pad)
__global__ __launch_bounds__(256, 2) void k_conv2(const _Float16* __restrict__ p1h,
                                                  const _Float16* __restrict__ wph,
                                                  const float* __restrict__ b2,
                                                  _Float16* __restrict__ p2h) {
    __shared__ __align__(16) _Float16 Al[8 * AIMG3];   // 59904 B
    int tid = threadIdx.x;
    int b0 = blockIdx.x * 8;

    {
        const uint4* src = (const uint4*)(p1h + (size_t)b0 * 3456);
        uint4* dst = (uint4*)Al;
        uint4 z = make_uint4(0u, 0u, 0u, 0u);
        for (int i = tid; i < 3744; i += 256) {
            int img = i / 468, r = i - img * 468;
            dst[i] = (r < 432) ? src[img * 432 + r] : z;
        }
    }
    __syncthreads();

    int wid = tid >> 6, lane = tid & 63;
    int kg = lane >> 4, rr = lane & 15;
    int Y = rr >> 3, xx = rr & 7;
    const _Float16* Ab0 = Al + (wid * 2) * AIMG3;
    const _Float16* Ab1 = Ab0 + AIMG3;
    const _Float16* abase[8];
#pragma unroll
    for (int my = 0; my < 4; ++my) {
        abase[my]     = Ab0 + ((2 * my + Y) * 12 + xx) * 24;
        abase[my + 4] = Ab1 + ((2 * my + Y) * 12 + xx) * 24;
    }
    const _Float16* bh_base = wph + rr * 32 + kg * 8;

    v4f acc[8][4];
#pragma unroll
    for (int my = 0; my < 8; ++my)
#pragma unroll
        for (int nt = 0; nt < 4; ++nt) acc[my][nt] = (v4f){0.f, 0.f, 0.f, 0.f};

#define AOFS(T)                                                               \
    ({                                                                        \
        int k0_ = (T) * 32 + kg * 8;                                          \
        int pix_ = (k0_ * 2731) >> 16;                                        \
        int icol_ = k0_ - pix_ * 24;                                          \
        int ky_ = (pix_ * 205) >> 10;                                         \
        int kx_ = pix_ - 5 * ky_;                                             \
        (ky_ * 12 + kx_) * 24 + icol_;                                        \
    })

    for (int u = 0; u < 9; ++u) {
        int t0 = 2 * u, t1 = 2 * u + 1;
        v8h bA[4], bB[4];
#pragma unroll
        for (int nt = 0; nt < 4; ++nt) {
            bA[nt] = *(const v8h*)(bh_base + t0 * 2048 + nt * 512);
            bB[nt] = *(const v8h*)(bh_base + t1 * 2048 + nt * 512);
        }
        int aofs0 = AOFS(t0), aofs1 = AOFS(t1);
        v8h afA[8], afB[8];
#pragma unroll
        for (int my = 0; my < 8; ++my) {
            afA[my] = *(const v8h*)(abase[my] + aofs0);
            afB[my] = *(const v8h*)(abase[my] + aofs1);
        }
        __builtin_amdgcn_s_setprio(1);
#pragma unroll
        for (int my = 0; my < 8; ++my)
#pragma unroll
            for (int nt = 0; nt < 4; ++nt)
                acc[my][nt] = __builtin_amdgcn_mfma_f32_16x16x32_f16(afA[my], bA[nt], acc[my][nt], 0, 0, 0);
#pragma unroll
        for (int my = 0; my < 8; ++my)
#pragma unroll
            for (int nt = 0; nt < 4; ++nt)
                acc[my][nt] = __builtin_amdgcn_mfma_f32_16x16x32_f16(afB[my], bB[nt], acc[my][nt], 0, 0, 0);
        __builtin_amdgcn_s_setprio(0);
    }
    {   // tail step t=18
        v8h bA[4], afA[8];
#pragma unroll
        for (int nt = 0; nt < 4; ++nt)
            bA[nt] = *(const v8h*)(bh_base + 18 * 2048 + nt * 512);
        int aofs0 = AOFS(18);
#pragma unroll
        for (int my = 0; my < 8; ++my)
            afA[my] = *(const v8h*)(abase[my] + aofs0);
        __builtin_amdgcn_s_setprio(1);
#pragma unroll
        for (int my = 0; my < 8; ++my)
#pragma unroll
            for (int nt = 0; nt < 4; ++nt)
                acc[my][nt] = __builtin_amdgcn_mfma_f32_16x16x32_f16(afA[my], bA[nt], acc[my][nt], 0, 0, 0);
        __builtin_amdgcn_s_setprio(0);
    }
#undef AOFS

#pragma unroll
    for (int h = 0; h < 2; ++h) {
        int imgg = b0 + wid * 2 + h;
#pragma unroll
        for (int nt = 0; nt < 4; ++nt) {
            int oc = nt * 16 + rr;
            float bias = (oc < 50) ? b2[oc] : 0.f;
#pragma unroll
            for (int my = 0; my < 4; ++my) {
                v4f a = acc[h * 4 + my][nt];
                float z0 = fmaxf(trunc13(a[0] + bias), 0.f);
                float z1 = fmaxf(trunc13(a[1] + bias), 0.f);
                float z2 = fmaxf(trunc13(a[2] + bias), 0.f);
                float z3 = fmaxf(trunc13(a[3] + bias), 0.f);
                float s0 = fmaxf(z0, z1), s2 = fmaxf(z2, z3);
                float o0 = fmaxf(s0, __shfl_xor(s0, 32, 64));
                float o2 = fmaxf(s2, __shfl_xor(s2, 32, 64));
                if (kg < 2 && oc < 50) {
                    p2h[(size_t)imgg * 800 + oc * 16 + my * 4 + 2 * kg]     = (_Float16)o0;
                    p2h[(size_t)imgg * 800 + oc * 16 + my * 4 + 2 * kg + 1] = (_Float16)o2;
                }
            }
        }
    }
}

// ---------------------------------------------------------------------------
// K3: fc1 via MFMA 16x16x32_f16, hi-only. BM=128 BN=64 BK=32, grid 32x8,
// 4 waves; A XOR-swizzled, B stride-5-granule (conflict-free); T14 dbuf.
// ---------------------------------------------------------------------------
__global__ __launch_bounds__(256) void k_fc1(const _Float16* __restrict__ Ah,
                                             const _Float16* __restrict__ Bp,
                                             const float* __restrict__ bias,
                                             _Float16* __restrict__ Hh) {
    __shared__ _Float16 Al[2][4096];
    __shared__ _Float16 Bl[2][2560];
    int tid = threadIdx.x;
    int i0 = blockIdx.x * 128, n0 = blockIdx.y * 64;
    int wid = tid >> 6, lane = tid & 63;
    int rr = lane & 15, kg = lane >> 4;

    int ca0 = tid, ca1 = tid + 256;
    int ra0_ = ca0 >> 2, qa0 = ca0 & 3, ra1_ = ca1 >> 2, qa1 = ca1 & 3;
    int aw0 = (ra0_ * 4 + (qa0 ^ ((ra0_ >> 1) & 3))) * 8;
    int aw1 = (ra1_ * 4 + (qa1 ^ ((ra1_ >> 1) & 3))) * 8;
    int bwB = ((tid >> 2) * 5 + (tid & 3)) * 8;

    uint4 xa0, xa1, xb0;
    auto loadT = [&](int t) {
        xa0 = *(const uint4*)(Ah + (size_t)(i0 + ra0_) * 800 + t * 32 + qa0 * 8);
        xa1 = *(const uint4*)(Ah + (size_t)(i0 + ra1_) * 800 + t * 32 + qa1 * 8);
        const uint4* g = (const uint4*)Bp + (size_t)t * 4096 + (size_t)n0 * 8;
        xb0 = g[(tid >> 2) * 8 + (tid & 3)];
    };
    auto writeT = [&](int buf) {
        *(uint4*)(&Al[buf][aw0]) = xa0;
        *(uint4*)(&Al[buf][aw1]) = xa1;
        *(uint4*)(&Bl[buf][bwB]) = xb0;
    };

    int aoff[2], bhoff[4];
#pragma unroll
    for (int mf = 0; mf < 2; ++mf) {
        int r = wid * 32 + mf * 16 + rr;
        aoff[mf] = (r * 4 + (kg ^ ((rr >> 1) & 3))) * 8;
    }
#pragma unroll
    for (int nf = 0; nf < 4; ++nf)
        bhoff[nf] = ((nf * 16 + rr) * 5 + kg) * 8;

    v4f zero = {0.f, 0.f, 0.f, 0.f};
    v4f acc[2][4];
#pragma unroll
    for (int mf = 0; mf < 2; ++mf)
#pragma unroll
        for (int nf = 0; nf < 4; ++nf) acc[mf][nf] = zero;

    loadT(0);
    writeT(0);
    __syncthreads();

    for (int t = 0; t < 25; ++t) {
        int cur = t & 1;
        if (t < 24) loadT(t + 1);
        v8h af[2], bh[4];
#pragma unroll
        for (int mf = 0; mf < 2; ++mf) af[mf] = *(const v8h*)(&Al[cur][aoff[mf]]);
#pragma unroll
        for (int nf = 0; nf < 4; ++nf) bh[nf] = *(const v8h*)(&Bl[cur][bhoff[nf]]);
#pragma unroll
        for (int mf = 0; mf < 2; ++mf)
#pragma unroll
            for (int nf = 0; nf < 4; ++nf)
                acc[mf][nf] = __builtin_amdgcn_mfma_f32_16x16x32_f16(af[mf], bh[nf], acc[mf][nf], 0, 0, 0);
        if (t < 24) writeT(cur ^ 1);
        __syncthreads();
    }

#pragma unroll
    for (int mf = 0; mf < 2; ++mf)
#pragma unroll
        for (int nf = 0; nf < 4; ++nf) {
            int col = n0 + nf * 16 + rr;
            float bs = bias[col < 500 ? col : 0];
#pragma unroll
            for (int j = 0; j < 4; ++j) {
                int row = i0 + wid * 32 + mf * 16 + kg * 4 + j;
                float v = fmaxf(trunc13(acc[mf][nf][j] + bs), 0.f);
                if (col < 500) Hh[(size_t)row * 512 + col] = (_Float16)v;
            }
        }
}

// ---------------------------------------------------------------------------
// K4: fc2 (500->10) + bias + trunc + log_softmax.  One wave per row, fp16 H.
// ---------------------------------------------------------------------------
__global__ __launch_bounds__(256) void k_fc2(const _Float16* __restrict__ Hh,
                                             const float* __restrict__ W,
                                             const float* __restrict__ bias,
                                             float* __restrict__ out) {
    int wave = threadIdx.x >> 6;
    int lane = threadIdx.x & 63;
    int i = blockIdx.x * 4 + wave;
    const _Float16* hrow = Hh + (size_t)i * 512;

    float p[10];
#pragma unroll
    for (int j = 0; j < 10; ++j) p[j] = 0.f;
    for (int k = lane; k < 500; k += 64) {
        float h = (float)hrow[k];
#pragma unroll
        for (int j = 0; j < 10; ++j) p[j] += h * W[j * 500 + k];
    }
#pragma unroll
    for (int j = 0; j < 10; ++j)
#pragma unroll
        for (int off = 32; off; off >>= 1) p[j] += __shfl_xor(p[j], off, 64);

    if (lane == 0) {
        float z[10], m = -1e30f;
#pragma unroll
        for (int j = 0; j < 10; ++j) {
            z[j] = trunc13(p[j] + bias[j]);
            m = fmaxf(m, z[j]);
        }
        float s = 0.f;
#pragma unroll
        for (int j = 0; j < 10; ++j) s += expf(z[j] - m);
        float lse = m + logf(s);
#pragma unroll
        for (int j = 0; j < 10; ++j) out[(size_t)i * 10 + j] = z[j] - lse;
    }
}

// ---------------------------------------------------------------------------
extern "C" void kernel_launch(void* const* d_in, const int* in_sizes, int n_in,
                              void* d_out, int out_size, void* d_ws, size_t ws_size,
                              hipStream_t stream) {
    const float* x   = (const float*)d_in[0];
    const float* w1  = (const float*)d_in[1];
    const float* b1  = (const float*)d_in[2];
    const float* w2  = (const float*)d_in[3];
    const float* b2  = (const float*)d_in[4];
    const float* wf1 = (const float*)d_in[5];
    const float* bf1 = (const float*)d_in[6];
    const float* wf2 = (const float*)d_in[7];
    const float* bf2 = (const float*)d_in[8];
    float* out = (float*)d_out;

    char* ws = (char*)d_ws;
    _Float16* p1h  = (_Float16*)(ws);                   // 28,311,552
    _Float16* p2h  = (_Float16*)(ws + 28311552);        //  6,553,600
    _Float16* h1h  = (_Float16*)(ws + 34865152);        //  4,194,304
    _Float16* wph  = (_Float16*)(ws + 39059456);        //     81,920
    _Float16* wpf1 = (_Float16*)(ws + 39141376);        //  1,638,400
    _Float16* wpc1 = (_Float16*)(ws + 40779776);        //      2,048

    k_prep<<<56, 256, 0, stream>>>(w1, w2, wf1, wpc1, wph, wpf1);
    k_conv1<<<1024, 256, 0, stream>>>(x, wpc1, b1, p1h);
    k_conv2<<<512, 256, 0, stream>>>(p1h, wph, b2, p2h);
    dim3 g3(32, 8);
    k_fc1<<<g3, 256, 0, stream>>>(p2h, wpf1, bf1, h1h);
    k_fc2<<<1024, 256, 0, stream>>>(h1h, wf2, bf2, out);
}